// Round 1
// baseline (184.621 us; speedup 1.0000x reference)
//
#include <hip/hip_runtime.h>
#include <math.h>

static constexpr int B_  = 2;
static constexpr int S_  = 2048;
static constexpr int E_  = 1024;
static constexpr int NH_ = 4;
static constexpr int HD_ = 256;
static constexpr int BH_ = B_ * NH_;

typedef __attribute__((ext_vector_type(8))) _Float16 half8;
typedef __attribute__((ext_vector_type(4))) float    f32x4;
typedef __attribute__((ext_vector_type(4))) _Float16 half4v;

// ---------------- Kernel 1: gates + fp16 Q/K + V-transpose (fused; unchanged R11) ----------------
__global__ __launch_bounds__(1024) void prep_kernel(
    const float* __restrict__ q, const float* __restrict__ k, const float* __restrict__ v,
    const float* __restrict__ igk, const float* __restrict__ igb,
    const float* __restrict__ fgk, const float* __restrict__ fgb,
    float* __restrict__ ig_out, float* __restrict__ fg_out,
    _Float16* __restrict__ Qh, _Float16* __restrict__ Kh, _Float16* __restrict__ Vt)
{
    __shared__ __align__(16) char PSM[98304];
    float4* wi = (float4*)PSM;          // [3072] 48 KB
    float4* wf = wi + 3 * E_;           // [3072] 48 KB

    const int t = threadIdx.x;
    #pragma unroll
    for (int i = 0; i < 3; ++i) {
        int e = t + 1024 * i;
        wi[e] = ((const float4*)igk)[e];
        wf[e] = ((const float4*)fgk)[e];
    }
    __syncthreads();

    const int wave = t >> 6;
    const int l    = t & 63;
    const int bs   = blockIdx.x * 16 + wave;     // b*S + s
    const int b = bs >> 11, s = bs & (S_ - 1);
    const float* qrow = q + (size_t)bs * E_;
    const float* krow = k + (size_t)bs * E_;
    const float* vrow = v + (size_t)bs * E_;

    float accI[4] = {0.f,0.f,0.f,0.f}, accF[4] = {0.f,0.f,0.f,0.f};
    #pragma unroll
    for (int j = 0; j < 48; ++j) {
        const int e = l + 64 * j;
        float g;
        if (j < 16)       g = qrow[e];
        else if (j < 32)  g = krow[e - E_];
        else              g = vrow[e - 2 * E_];
        if (j < 16) {
            int hh = e >> 8, d = e & 255;
            Qh[(((size_t)(b * NH_ + hh)) * S_ + s) * HD_ + d] = (_Float16)(g * 0.0625f);
        } else if (j < 32) {
            int e2 = e - E_; int hh = e2 >> 8, d = e2 & 255;
            Kh[(((size_t)(b * NH_ + hh)) * S_ + s) * HD_ + d] = (_Float16)g;
        }
        float4 wiv = wi[e];
        float4 wfv = wf[e];
        accI[0] = fmaf(g, wiv.x, accI[0]); accI[1] = fmaf(g, wiv.y, accI[1]);
        accI[2] = fmaf(g, wiv.z, accI[2]); accI[3] = fmaf(g, wiv.w, accI[3]);
        accF[0] = fmaf(g, wfv.x, accF[0]); accF[1] = fmaf(g, wfv.y, accF[1]);
        accF[2] = fmaf(g, wfv.z, accF[2]); accF[3] = fmaf(g, wfv.w, accF[3]);
    }
    #pragma unroll
    for (int m = 1; m < 64; m <<= 1) {
        #pragma unroll
        for (int h = 0; h < 4; ++h) {
            accI[h] += __shfl_xor(accI[h], m);
            accF[h] += __shfl_xor(accF[h], m);
        }
    }
    if (l == 0) {
        #pragma unroll
        for (int h = 0; h < 4; ++h) {
            ig_out[((size_t)(b * NH_ + h)) * S_ + s] = accI[h] + igb[h];
            fg_out[((size_t)(b * NH_ + h)) * S_ + s] = accF[h] + fgb[h];
        }
    }

    __syncthreads();    // all weight reads done; reuse LDS for transpose
    {
        float (*tile)[65] = (float(*)[65])(PSM + (t >> 8) * 16640);
        const int tid = t & 255;
        const int m  = blockIdx.x * 4 + (t >> 8);    // 0..1023
        const int bh = m & 7;
        const int sb = (m >> 3) & 31;
        const int db = m >> 8;
        const int bb = bh >> 2, hh = bh & 3;
        const int j4 = (tid & 15) * 4;
        const int i0 = tid >> 4;
        const float* src = v + ((size_t)(bb * S_ + sb * 64)) * E_ + hh * HD_ + db * 64;
        #pragma unroll
        for (int p = 0; p < 4; ++p) {
            int i = i0 + p * 16;
            float4 val = *(const float4*)(src + (size_t)i * E_ + j4);
            tile[i][j4] = val.x; tile[i][j4+1] = val.y; tile[i][j4+2] = val.z; tile[i][j4+3] = val.w;
        }
        __syncthreads();
        const int s4 = (tid & 15) * 4;
        const int d0 = tid >> 4;
        _Float16* dst = Vt + ((size_t)bh * HD_ + db * 64) * S_ + sb * 64;
        #pragma unroll
        for (int p = 0; p < 4; ++p) {
            int d = d0 + p * 16;
            half4v pk;
            pk.x = (_Float16)tile[s4][d];   pk.y = (_Float16)tile[s4+1][d];
            pk.z = (_Float16)tile[s4+2][d]; pk.w = (_Float16)tile[s4+3][d];
            *(half4v*)(dst + (size_t)d * S_ + s4) = pk;
        }
    }
}

// ---------------- Kernel 2 (R12): direct-L2 K/V fragments, P-only LDS, 1 barrier/tile ----------------
// Old structure staged K/V via LDS, but every wave read an EXCLUSIVE slice (zero
// cross-wave reuse): ~217 KB LDS + 3 barriers per 64-col tile -> MfmaUtil 10%.
// New: KVBLK=128. 8 waves = 8 disjoint 16-col groups (QK) / 8 disjoint 32-wide
// n-slices (PV). Each wave holds BOTH 16-row halves of the 32 Q-rows in regs.
// K/V fragments come straight from per-XCD L2 (head = 2 MB, resident; bh = z&7
// keeps one head per XCD). Only the 32x128 P tile crosses LDS: XOR-swizzled
// (byte ^= (row&7)<<4) and double-buffered -> exactly one barrier per K-tile.
static constexpr int PB_BYTES = 32 * 128 * 2;          // one P buffer (8 KB)
static constexpr int OFF_AMM = 2 * PB_BYTES;           // 16384
static constexpr int OFF_G   = OFF_AMM + S_ * 4;       // 24576
static constexpr int OFF_M   = OFF_G + S_ * 4;         // 32768
static constexpr int OFF_RS  = OFF_M + S_ * 4;         // 40960
static constexpr int OFF_SS  = OFF_RS + 8 * 32 * 4;    // 41984
static constexpr int OFF_WR  = OFF_SS + 8 * 32 * 4;    // 43008
static constexpr int SMB     = OFF_WR + 64;            // 43072

__global__ __launch_bounds__(512, 2) void mlstm_kernel(
    const _Float16* __restrict__ Qh, const _Float16* __restrict__ Kh,
    const _Float16* __restrict__ Vt,
    const float* __restrict__ ig, const float* __restrict__ fg,
    const float* __restrict__ rms_scale, float* __restrict__ out)
{
    __shared__ __align__(16) char SMEM[SMB];
    char*  Pb    = SMEM;                             // [2][32][128] halfs, swizzled
    float* sAmM  = (float*)(SMEM + OFF_AMM);         // [S]
    float* sG    = (float*)(SMEM + OFF_G);           // [S]
    float* sM    = (float*)(SMEM + OFF_M);           // [S]
    float* rsumP = (float*)(SMEM + OFF_RS);          // [8][32]
    float* ssP   = (float*)(SMEM + OFF_SS);          // [8][32]
    float* wred  = (float*)(SMEM + OFF_WR);          // [8] + [8]
    float* wred2 = wred + 8;

    const int z  = blockIdx.x;
    const int bh = z & 7;                 // one head per XCD
    const int u  = z >> 3;                // 0..31
    const int b  = bh >> 2, h = bh & 3;
    const int t  = threadIdx.x;
    const int w  = t >> 6;                // 0..7
    const int l  = t & 63;
    const int col  = l & 15;
    const int quad = l >> 4;
    const int qo   = quad * 8;

    // ---- scan prologue: wave-level shfl scans (3 barriers instead of 36) ----
    {
        const float* fgp = fg + (size_t)bh * S_;
        const float* igp = ig + (size_t)bh * S_;
        float4 fx = *(const float4*)(fgp + t * 4);
        float4 ix = *(const float4*)(igp + t * 4);
        float xi[4] = {fx.x, fx.y, fx.z, fx.w};
        float gi[4] = {ix.x, ix.y, ix.z, ix.w};
        float ls[4];
        float run = 0.f;
        #pragma unroll
        for (int i = 0; i < 4; ++i) {
            float x = xi[i];
            float lg = (x >= 0.f) ? -log1pf(expf(-x)) : (x - log1pf(expf(x)));
            run += lg;
            ls[i] = run;
        }
        const float own = run;
        #pragma unroll
        for (int m = 1; m < 64; m <<= 1) {
            float o = __shfl_up(run, m);
            if (l >= m) run += o;
        }
        if (l == 63) wred[w] = run;
        __syncthreads();
        float wpre = 0.f;
        for (int ww = 0; ww < w; ++ww) wpre += wred[ww];
        const float exclT = wpre + run - own;
        float A[4], g[4], gm[4];
        float rmax = -__builtin_inff();
        #pragma unroll
        for (int i = 0; i < 4; ++i) {
            A[i] = exclT + ls[i];
            g[i] = gi[i] - A[i];
            rmax = fmaxf(rmax, g[i]);
            gm[i] = rmax;
        }
        float sm = rmax;
        #pragma unroll
        for (int m = 1; m < 64; m <<= 1) {
            float o = __shfl_up(sm, m);
            if (l >= m) sm = fmaxf(sm, o);
        }
        if (l == 63) wred2[w] = sm;
        __syncthreads();
        float exm = -__builtin_inff();
        for (int ww = 0; ww < w; ++ww) exm = fmaxf(exm, wred2[ww]);
        float up = __shfl_up(sm, 1);
        if (l > 0) exm = fmaxf(exm, up);
        #pragma unroll
        for (int i = 0; i < 4; ++i) {
            float cm = fmaxf(exm, gm[i]);
            float Mi = A[i] + cm;
            sAmM[t * 4 + i] = A[i] - Mi;
            sG[t * 4 + i]   = g[i];
            sM[t * 4 + i]   = Mi;
        }
        __syncthreads();
    }

    const _Float16* Qp  = Qh + (size_t)bh * S_ * HD_;
    const _Float16* Kp  = Kh + (size_t)bh * S_ * HD_;
    const _Float16* Vtp = Vt + (size_t)bh * HD_ * S_;

    const float rsc0 = 1.f + rms_scale[w * 32 + col];
    const float rsc1 = 1.f + rms_scale[w * 32 + 16 + col];

    int buf = 0;

    for (int pass = 0; pass < 2; ++pass) {
        const int rb = pass ? (63 - u) : u;
        const int rowbase = rb * 32;
        const int Tt = (rb >> 2) + 1;

        // Q fragments: both 16-row halves (64 VGPR), reused across all tiles
        half8 qf0[8], qf1[8];
        #pragma unroll
        for (int kk = 0; kk < 8; ++kk) {
            qf0[kk] = *(const half8*)(Qp + (size_t)(rowbase + col) * HD_ + kk * 32 + qo);
            qf1[kk] = *(const half8*)(Qp + (size_t)(rowbase + 16 + col) * HD_ + kk * 32 + qo);
        }
        float amM0[4], amM1[4];
        #pragma unroll
        for (int rr = 0; rr < 4; ++rr) {
            amM0[rr] = sAmM[rowbase + quad * 4 + rr];
            amM1[rr] = sAmM[rowbase + 16 + quad * 4 + rr];
        }

        f32x4 acc[4];
        #pragma unroll
        for (int i = 0; i < 4; ++i) acc[i] = (f32x4){0.f, 0.f, 0.f, 0.f};
        float rs0[4] = {0.f,0.f,0.f,0.f}, rs1[4] = {0.f,0.f,0.f,0.f};

        // K fragment prefetch for tile 0 (this wave's exclusive 16 K-rows)
        const _Float16* kcol_base = Kp + (size_t)(w * 16 + col) * HD_ + qo;
        half8 kf[8];
        #pragma unroll
        for (int kk = 0; kk < 8; ++kk)
            kf[kk] = *(const half8*)(kcol_base + kk * 32);

        half8 vf[8];
        for (int jt = 0; jt < Tt; ++jt) {
            const int c0 = jt << 7;
            // V fragments for THIS tile (used after the barrier -> long latency window)
            #pragma unroll
            for (int nsub = 0; nsub < 2; ++nsub) {
                #pragma unroll
                for (int kh = 0; kh < 4; ++kh)
                    vf[nsub * 4 + kh] = *(const half8*)(Vtp
                        + (size_t)(w * 32 + nsub * 16 + col) * S_ + c0 + kh * 32 + qo);
            }
            // QK^T: 32 rows x this wave's 16 cols, K straight from L2
            f32x4 sc0 = (f32x4){0.f,0.f,0.f,0.f}, sc1 = (f32x4){0.f,0.f,0.f,0.f};
            #pragma unroll
            for (int kk = 0; kk < 8; ++kk) {
                sc0 = __builtin_amdgcn_mfma_f32_16x16x32_f16(qf0[kk], kf[kk], sc0, 0, 0, 0);
                sc1 = __builtin_amdgcn_mfma_f32_16x16x32_f16(qf1[kk], kf[kk], sc1, 0, 0, 0);
            }
            // K prefetch for next tile (covered by fixup + barrier + PV)
            if (jt + 1 < Tt) {
                const _Float16* kb = kcol_base + (size_t)(c0 + 128) * HD_;
                #pragma unroll
                for (int kk = 0; kk < 8; ++kk)
                    kf[kk] = *(const half8*)(kb + kk * 32);
            }
            // fixup: p = s * exp(AmM[row] + G[col]), causal mask, fp16 -> swizzled P
            const int gcol = c0 + w * 16 + col;
            const float gv = sG[gcol];
            char* pbC = Pb + buf * PB_BYTES;
            const int hcb = (w * 16 + col) << 1;
            #pragma unroll
            for (int rr = 0; rr < 4; ++rr) {
                const int r0 = quad * 4 + rr;
                const int sw = (r0 & 7) << 4;
                float e0 = __expf(amM0[rr] + gv);
                float p0 = (gcol <= rowbase + r0) ? sc0[rr] * e0 : 0.f;
                rs0[rr] += p0;
                *(_Float16*)(pbC + (((r0 << 8) + hcb) ^ sw)) = (_Float16)p0;
                float e1 = __expf(amM1[rr] + gv);
                float p1 = (gcol <= rowbase + 16 + r0) ? sc1[rr] * e1 : 0.f;
                rs1[rr] += p1;
                const int r1 = r0 + 16;
                *(_Float16*)(pbC + (((r1 << 8) + hcb) ^ sw)) = (_Float16)p1;
            }
            __syncthreads();              // publish P (only barrier in the tile)
            // PV: A = P[32x128] from swizzled LDS, B = V^T n-slice (w*32..+32) from L2
            #pragma unroll
            for (int rsub = 0; rsub < 2; ++rsub) {
                const int prow = rsub * 16 + col;
                half8 af[4];
                #pragma unroll
                for (int kh = 0; kh < 4; ++kh)
                    af[kh] = *(const half8*)(pbC
                        + ((prow << 8) + ((kh * 64 + qo * 2) ^ ((col & 7) << 4))));
                #pragma unroll
                for (int kh = 0; kh < 4; ++kh) {
                    acc[rsub * 2 + 0] = __builtin_amdgcn_mfma_f32_16x16x32_f16(af[kh], vf[kh],     acc[rsub * 2 + 0], 0, 0, 0);
                    acc[rsub * 2 + 1] = __builtin_amdgcn_mfma_f32_16x16x32_f16(af[kh], vf[4 + kh], acc[rsub * 2 + 1], 0, 0, 0);
                }
            }
            buf ^= 1;
        }

        // ---- epilogue: rowsum across 8 col-waves, normalize, RMSNorm, store slice ----
        #pragma unroll
        for (int m = 1; m < 16; m <<= 1) {
            #pragma unroll
            for (int rr = 0; rr < 4; ++rr) {
                rs0[rr] += __shfl_xor(rs0[rr], m);
                rs1[rr] += __shfl_xor(rs1[rr], m);
            }
        }
        if (col == 0) {
            #pragma unroll
            for (int rr = 0; rr < 4; ++rr) {
                rsumP[w * 32 + quad * 4 + rr]      = rs0[rr];
                rsumP[w * 32 + 16 + quad * 4 + rr] = rs1[rr];
            }
        }
        __syncthreads();
        float inv0[4], inv1[4];
        #pragma unroll
        for (int rr = 0; rr < 4; ++rr) {
            const int r0 = quad * 4 + rr;
            float tot0 = 0.f, tot1 = 0.f;
            #pragma unroll
            for (int ww = 0; ww < 8; ++ww) {
                tot0 += rsumP[ww * 32 + r0];
                tot1 += rsumP[ww * 32 + 16 + r0];
            }
            float M0 = sM[rowbase + r0];
            float M1 = sM[rowbase + 16 + r0];
            inv0[rr] = 1.0f / (fmaxf(tot0, __expf(-M0)) + 1e-6f);
            inv1[rr] = 1.0f / (fmaxf(tot1, __expf(-M1)) + 1e-6f);
        }
        float ss0[4] = {0.f,0.f,0.f,0.f}, ss1[4] = {0.f,0.f,0.f,0.f};
        #pragma unroll
        for (int nsub = 0; nsub < 2; ++nsub) {
            #pragma unroll
            for (int rr = 0; rr < 4; ++rr) {
                float h0 = acc[nsub][rr] * inv0[rr];
                acc[nsub][rr] = h0;
                ss0[rr] = fmaf(h0, h0, ss0[rr]);
                float h1 = acc[2 + nsub][rr] * inv1[rr];
                acc[2 + nsub][rr] = h1;
                ss1[rr] = fmaf(h1, h1, ss1[rr]);
            }
        }
        #pragma unroll
        for (int m = 1; m < 16; m <<= 1) {
            #pragma unroll
            for (int rr = 0; rr < 4; ++rr) {
                ss0[rr] += __shfl_xor(ss0[rr], m);
                ss1[rr] += __shfl_xor(ss1[rr], m);
            }
        }
        if (col == 0) {
            #pragma unroll
            for (int rr = 0; rr < 4; ++rr) {
                ssP[w * 32 + quad * 4 + rr]      = ss0[rr];
                ssP[w * 32 + 16 + quad * 4 + rr] = ss1[rr];
            }
        }
        __syncthreads();
        #pragma unroll
        for (int rr = 0; rr < 4; ++rr) {
            const int r0 = quad * 4 + rr;
            float sst0 = 0.f, sst1 = 0.f;
            #pragma unroll
            for (int ww = 0; ww < 8; ++ww) {
                sst0 += ssP[ww * 32 + r0];
                sst1 += ssP[ww * 32 + 16 + r0];
            }
            float rstd0 = rsqrtf(sst0 * (1.0f / HD_) + 1e-6f);
            float rstd1 = rsqrtf(sst1 * (1.0f / HD_) + 1e-6f);
            float* o0 = out + ((size_t)(b * S_ + rowbase + r0)) * E_ + h * HD_ + w * 32;
            float* o1 = out + ((size_t)(b * S_ + rowbase + 16 + r0)) * E_ + h * HD_ + w * 32;
            o0[col]      = acc[0][rr] * rstd0 * rsc0;
            o0[16 + col] = acc[1][rr] * rstd0 * rsc1;
            o1[col]      = acc[2][rr] * rstd1 * rsc0;
            o1[16 + col] = acc[3][rr] * rstd1 * rsc1;
        }
        __syncthreads();   // rsumP/ssP retired before next pass reuses them
    }
}

extern "C" void kernel_launch(void* const* d_in, const int* in_sizes, int n_in,
                              void* d_out, int out_size, void* d_ws, size_t ws_size,
                              hipStream_t stream) {
    (void)in_sizes; (void)n_in; (void)out_size; (void)ws_size;
    const float* q   = (const float*)d_in[0];
    const float* k   = (const float*)d_in[1];
    const float* v   = (const float*)d_in[2];
    const float* igk = (const float*)d_in[3];
    const float* igb = (const float*)d_in[4];
    const float* fgk = (const float*)d_in[5];
    const float* fgb = (const float*)d_in[6];
    const float* rsc = (const float*)d_in[7];
    float* out = (float*)d_out;

    float* ws  = (float*)d_ws;
    float* ig  = ws;                          // BH*S each
    float* fg  = ws + (size_t)BH_ * S_;
    _Float16* Qh = (_Float16*)(ws + (size_t)2 * BH_ * S_);
    _Float16* Kh = Qh + (size_t)BH_ * S_ * HD_;
    _Float16* Vt = Kh + (size_t)BH_ * S_ * HD_;

    prep_kernel<<<B_ * S_ / 16, 1024, 0, stream>>>(q, k, v, igk, igb, fgk, fgb,
                                                   ig, fg, Qh, Kh, Vt);
    mlstm_kernel<<<BH_ * 32, 512, 0, stream>>>(Qh, Kh, Vt, ig, fg, rsc, out);
}